// Round 5
// baseline (4082.829 us; speedup 1.0000x reference)
//
#include <hip/hip_runtime.h>
#include <hip/hip_bf16.h>
#include <stdint.h>
#include <type_traits>

#define SUBU 20
#define E_NO 2000
#define I_NO 500
#define T_DATA 20000
#define T_SYNK 200
#define T_HISTK 50
#define SBAS 3
#define HBAS 3
#define TPAD 20096          // 1256 * 16
#define KSTORE 12

// workspace float offsets
#define OFF_SYN  0          // [20][TPAD]  c[s][t] = TK*(syn + theta + rowsum)
#define OFF_INE  401920     // [20][TPAD]
#define OFF_INI  803840     // [20][TPAD]  (reused as Y f32 by scan)
#define OFF_KE   1205760    // [20][200]
#define OFF_KI   1209760    // [20][200]
#define OFF_IIR  1213760    // [20][16] folded IIR consts (A-side TK-scaled)
#define OFF_MW   1214760    // [20][KSTORE]  fallback: mwp = -2*TK*m
#define OFF_MIDX 1215000    // [20][KSTORE] ints (fallback)
#define OFF_PAR  1215240    // TK*(theta+rowsum)[20], wsub0, vo, ksel(int at +23)
#define OFF_FLAG 1215264    // int bf16 flag
#define OFF_TAB  1215280    // [20][96] 2-step tables
#define TSTR     96
#define OFF_Y    OFF_INI

#define TKC 2.8853900817779268f   // 2*log2(e)

__device__ __forceinline__ float bf2f(unsigned short u){
  unsigned v = ((unsigned)u) << 16; float f; __builtin_memcpy(&f, &v, 4); return f;
}
__device__ __forceinline__ float ldany(const void* p, int i, int bf){
  return bf ? bf2f(((const unsigned short*)p)[i]) : ((const float*)p)[i];
}
__device__ __forceinline__ float ex2(float x){ return __builtin_amdgcn_exp2f(x); }
__device__ __forceinline__ float rcpa(float x){ return __builtin_amdgcn_rcpf(x); }
__device__ __forceinline__ float bperm(int addr, float src){
  return __int_as_float(__builtin_amdgcn_ds_bpermute(addr, __float_as_int(src)));
}

// ---------------- dtype detection: S_e is exactly {0,1} -------------------
__global__ __launch_bounds__(256) void k_detect(const void* s_e, int* flag){
  __shared__ int found;
  if (threadIdx.x == 0) found = 0;
  __syncthreads();
  const unsigned* w = (const unsigned*)s_e;
  int hit = 0;
  for (int i = threadIdx.x; i < 8192; i += 256){
    unsigned x = w[i];
    if (x == 0x00003F80u || x == 0x3F803F80u) hit = 1;   // bf16 1.0 patterns
  }
  if (hit) atomicOr(&found, 1);
  __syncthreads();
  if (threadIdx.x == 0) *flag = found;
}

// ---------------- precompute: syn kernels, folded IIR, tables, params -----
__global__ __launch_bounds__(512) void k_prep(
    const void* Cden, const void* Wsyn, const void* Tausyn, const void* Dsyn,
    const void* Whist, const void* Tauhist, const void* Dhist,
    const void* Wsub, const void* Vo, const void* Theta, float* ws){
  int* wsi = (int*)ws;
  const int bf = wsi[OFF_FLAG];
  const int tx = threadIdx.x;
  __shared__ int mx;
  if (tx == 0) mx = 0;
  __syncthreads();
  // synaptic kernels ke/ki [20][200]
  for (int idx = tx; idx < SUBU * T_SYNK; idx += 512){
    int s = idx / T_SYNK, t = idx % T_SYNK;
    for (int c = 0; c < 2; ++c){
      float delta = __expf(ldany(Dsyn, s*2 + c, bf));
      float acc = 0.f;
      for (int b = 0; b < SBAS; ++b){
        float tau = __expf(ldany(Tausyn, b*2 + c, bf));
        float w   = ldany(Wsyn, (s*SBAS + b)*2 + c, bf);
        float tt  = fmaxf((float)t - delta, 0.f) / tau;
        acc += w * tt * __expf(-tt);
      }
      ws[(c == 0 ? OFF_KE : OFF_KI) + s*T_SYNK + t] = acc;
    }
  }
  // folded per-lane IIR constants; A-side carries TK*w
  if (tx < SUBU * HBAS){
    int s = tx / HBAS, b = tx % HBAS;
    float tau = __expf(ldany(Tauhist, b, bf));
    float w   = TKC * ldany(Whist, s*HBAS + b, bf);   // TK fold
    float dl  = ldany(Dhist, s, bf);
    float rho = __expf(-1.f / tau);
    float e1  = __expf(-(1.f - dl) / tau);
    float g1  = ((1.f - dl) / tau) * e1;
    float kap = rho / tau;
    float* c = ws + OFF_IIR + s*16 + b*4;
    c[0] = rho;          // decay
    c[1] = w * kap;      // E -> A  (TK-scaled)
    c[2] = w * g1;       // y_new into A (TK-scaled)
    c[3] = e1;           // y_new into E (unscaled)
    if (b == 2){         // slow basis window-correction taps
      float e49 = __expf(-(49.f - dl) / tau);
      float g49 = ((49.f - dl) / tau) * e49;
      ws[OFF_IIR + s*16 + 12] = w * (rho*g49 + kap*e49);  // TK-scaled
      ws[OFF_IIR + s*16 + 13] = rho * e49;                // E-side, unscaled
    }
  }
  // sparse tables
  if (tx < SUBU){
    int s = tx, cntf = 0, cnt12 = 0;
    float rowsum = 0.f;
    int idx6[6]; float w6[6];
    for (int sp = 0; sp < SUBU; ++sp){
      float c = ldany(Cden, s*SUBU + sp, bf);
      if (c != 0.f){
        float m = c * ldany(Wsub, sp, bf);
        rowsum += m;
        if (cntf < 6){ idx6[cntf] = sp; w6[cntf] = -2.f * TKC * m; }
        ++cntf;
        if (cnt12 < KSTORE){
          ws[OFF_MW + s*KSTORE + cnt12]  = -2.f * TKC * m;
          wsi[OFF_MIDX + s*KSTORE + cnt12] = sp;
          ++cnt12;
        }
      }
    }
    for (int k = cnt12; k < KSTORE; ++k){
      ws[OFF_MW + s*KSTORE + k] = 0.f; wsi[OFF_MIDX + s*KSTORE + k] = 0;
    }
    // 2-step tables: mwO[6], madO[6], mw2[6][6], mad2[6][6]
    float* tb = ws + OFF_TAB + s*TSTR; int* tbi = (int*)tb;
    for (int d = 0; d < 6; ++d){
      bool v = (d < cntf) && (d < 6);
      tb[d]     = v ? w6[d] : 0.f;
      tbi[6+d]  = v ? idx6[d]*4 : 0;
      int c2 = 0;
      if (v){
        int j = idx6[d];
        for (int sp = 0; sp < SUBU && c2 < 6; ++sp){
          float c = ldany(Cden, j*SUBU + sp, bf);
          if (c != 0.f){
            tb[12 + d*6 + c2]  = -2.f * TKC * c * ldany(Wsub, sp, bf);
            tbi[48 + d*6 + c2] = sp*4;
            ++c2;
          }
        }
      }
      for (int k = c2; k < 6; ++k){ tb[12+d*6+k] = 0.f; tbi[48+d*6+k] = 0; }
    }
    atomicMax(&mx, cntf);
    ws[OFF_PAR + s] = TKC * (ldany(Theta, s, bf) + rowsum);
  }
  __syncthreads();
  if (tx == 0){
    ws[OFF_PAR + SUBU]     = ldany(Wsub, 0, bf);
    ws[OFF_PAR + SUBU + 1] = ldany(Vo, 0, bf);
    int D = mx;
    wsi[OFF_PAR + 23] = (D <= 3) ? 3 : (D <= 6 ? D : 12);
  }
}

// ---------------- skinny GEMM: in_T[s][t] = sum_e S[t][e]*C[s][e] ---------
template<int BF>
__device__ __forceinline__ void gemm_impl(const void* S, const void* C, int W,
                                          float* dst, int t0, int lane){
  float acc[4][SUBU];
  #pragma unroll
  for (int r = 0; r < 4; ++r)
    #pragma unroll
    for (int s = 0; s < SUBU; ++s) acc[r][s] = 0.f;
  for (int e = lane; e < W; e += 64){
    float s0 = ldany(S, (t0+0)*W + e, BF);
    float s1 = ldany(S, (t0+1)*W + e, BF);
    float s2 = ldany(S, (t0+2)*W + e, BF);
    float s3 = ldany(S, (t0+3)*W + e, BF);
    #pragma unroll
    for (int s = 0; s < SUBU; ++s){
      float c = ldany(C, s*W + e, BF);
      acc[0][s] = fmaf(s0, c, acc[0][s]);
      acc[1][s] = fmaf(s1, c, acc[1][s]);
      acc[2][s] = fmaf(s2, c, acc[2][s]);
      acc[3][s] = fmaf(s3, c, acc[3][s]);
    }
  }
  #pragma unroll
  for (int r = 0; r < 4; ++r){
    #pragma unroll
    for (int s = 0; s < SUBU; ++s){
      float v = acc[r][s];
      #pragma unroll
      for (int m = 32; m >= 1; m >>= 1) v += __shfl_xor(v, m, 64);
      if (lane == 0) dst[s*TPAD + t0 + r] = v;
    }
  }
}

__global__ __launch_bounds__(64) void k_gemm(const void* S, const void* C, int W,
                                             float* dst, const int* flagp){
  int t0 = blockIdx.x * 4, lane = threadIdx.x;
  if (*flagp) gemm_impl<1>(S, C, W, dst, t0, lane);
  else        gemm_impl<0>(S, C, W, dst, t0, lane);
}

// ---------------- causal conv (+theta/rowsum fold, TK scale): c[s][t] -----
__global__ __launch_bounds__(256) void k_conv(float* ws){
  const int s  = blockIdx.y;
  const int t0 = blockIdx.x * 256;
  const float* ine = ws + OFF_INE + s*TPAD;
  const float* ini = ws + OFF_INI + s*TPAD;
  __shared__ float eL[455], iL[455], keL[T_SYNK], kiL[T_SYNK];
  for (int j = threadIdx.x; j < 455; j += 256){
    int t = t0 - 199 + j;
    bool ok = (t >= 0 && t < TPAD);
    eL[j] = ok ? ine[t] : 0.f;
    iL[j] = ok ? ini[t] : 0.f;
  }
  for (int j = threadIdx.x; j < T_SYNK; j += 256){
    keL[j] = ws[OFF_KE + s*T_SYNK + j];
    kiL[j] = ws[OFF_KI + s*T_SYNK + j];
  }
  __syncthreads();
  int t = t0 + threadIdx.x;
  if (t < TPAD){
    float a0 = 0.f, a1 = 0.f;
    #pragma unroll 4
    for (int k = 0; k < T_SYNK; ++k){
      a0 = fmaf(keL[k], eL[threadIdx.x + 199 - k], a0);
      a1 = fmaf(kiL[k], iL[threadIdx.x + 199 - k], a1);
    }
    ws[OFF_SYN + s*TPAD + t] = fmaf(TKC, a0 + a1, ws[OFF_PAR + s]);
  }
}

// ---------------- static component helpers --------------------------------
__device__ __forceinline__ float get9(const float4& a, const float4& b,
                                      const float4& p, int i){
  if (i >= 8) return p.x;
  const float4& q = (i < 4) ? a : b;
  int r = i & 3;
  return (r == 0) ? q.x : ((r == 1) ? q.y : ((r == 2) ? q.z : q.w));
}
__device__ __forceinline__ void set8(float4& a, float4& b, int i, float v){
  float4& q = (i < 4) ? a : b;
  int r = i & 3;
  if (r == 0) q.x = v; else if (r == 1) q.y = v; else if (r == 2) q.z = v; else q.w = v;
}
__device__ __forceinline__ float get4(const float4& a, const float4& b,
                                      const float4& c, const float4& d, int u){
  const float4& q = (u < 4) ? a : ((u < 8) ? b : ((u < 12) ? c : d));
  int r = u & 3;
  return (r == 0) ? q.x : ((r == 1) ? q.y : ((r == 2) ? q.z : q.w));
}
__device__ __forceinline__ void set4(float4& a, float4& b, float4& c, float4& d,
                                     int u, float v){
  float4& q = (u < 4) ? a : ((u < 8) ? b : ((u < 12) ? c : d));
  int r = u & 3;
  if (r == 0) q.x = v; else if (r == 1) q.y = v; else if (r == 2) q.z = v; else q.w = v;
}

// ---------------- 2-step scan: one gather round per two timesteps ---------
template<int D>
__global__ __launch_bounds__(64, 1) void k_scan2(float* ws, float* yout){
  const int* wsi = (const int*)ws;
  if (wsi[OFF_PAR + 23] != D) return;
  const int lane = threadIdx.x;
  const int s = lane < SUBU ? lane : SUBU - 1;
  const float* tb = ws + OFF_TAB + s*TSTR;
  const int* tbi = (const int*)tb;
  float mwO[D]; int madO[D];
  float mw2[D][D]; int mad2[D][D];
  #pragma unroll
  for (int d = 0; d < D; ++d){ mwO[d] = tb[d]; madO[d] = tbi[6+d]; }
  #pragma unroll
  for (int d = 0; d < D; ++d)
    #pragma unroll
    for (int k = 0; k < D; ++k){ mw2[d][k] = tb[12+d*6+k]; mad2[d][k] = tbi[48+d*6+k]; }
  const float* cc = ws + OFF_IIR + s*16;
  const float rh0 = cc[0],  kp0 = cc[1],  ay0 = cc[2],  ey0 = cc[3];
  const float rh1 = cc[4],  kp1 = cc[5],  ay1 = cc[6],  ey1 = cc[7];
  const float rh2 = cc[8],  kp2 = cc[9],  ay2 = cc[10], ey2 = cc[11];
  const float cA  = cc[12], cE  = cc[13];
  const float wsub0 = ws[OFF_PAR + SUBU];
  const float vo    = ws[OFF_PAR + SUBU + 1];
  const float* syncol = ws + OFF_SYN + s*TPAD;

  constexpr int YHN = (D <= 4) ? 66 : 58;
  float yhv[YHN];
  #pragma unroll
  for (int j = 0; j < YHN; ++j) yhv[j] = 0.f;
  float A0=0.f,E0=0.f,A1=0.f,E1=0.f,A2=0.f,E2=0.f;
  float rO[D], r2[D][D], Q[D];
  #pragma unroll
  for (int d = 0; d < D; ++d){
    rO[d] = 0.5f;
    #pragma unroll
    for (int k = 0; k < D; ++k) r2[d][k] = 0.5f;
  }
  float4 u0 = *(const float4*)(syncol + 0);
  float4 u1 = *(const float4*)(syncol + 4);
  float4 n0, n1;
  float xpreS = u0.x;
  #pragma unroll
  for (int d = 0; d < D; ++d) Q[d] = bperm(madO[d], xpreS);   // C'[0,j]
  int tbase = 0;

  auto block8 = [&](auto OFS_, float4& c0, float4& c1, float4& p0, float4& p1){
    constexpr int OFS = decltype(OFS_)::value;
    const float4* src = (const float4*)(syncol + tbase + 8);
    p0 = src[0]; p1 = src[1];
    float4 ob0, ob1;
    #pragma unroll
    for (int u = 0; u < 4; ++u){
      const int u2 = 2*u;
      // IIR update1 (state -> t+1): pure local, off the gather chain
      float ypm1 = yhv[OFS + u2 + 49];     // y[t-1]
      float yo50 = yhv[OFS + u2];          // y[t-50]
      float A0n = fmaf(rh0, A0, fmaf(kp0, E0, ay0 * ypm1));
      E0 = fmaf(rh0, E0, ey0 * ypm1); A0 = A0n;
      float A1n = fmaf(rh1, A1, fmaf(kp1, E1, ay1 * ypm1));
      E1 = fmaf(rh1, E1, ey1 * ypm1); A1 = A1n;
      float A2n = fmaf(rh2, A2, fmaf(kp2, E2, fmaf(-cA, yo50, ay2 * ypm1)));
      E2 = fmaf(rh2, E2, fmaf(-cE, yo50, ey2 * ypm1)); A2 = A2n;
      float xpre1 = get9(c0, c1, p0, u2 + 1) + ((A0 + A1) + A2);
      // own even step t
      float Xe;
      { float a0 = fmaf(mwO[0], rO[0], xpreS), a1 = 0.f;
        #pragma unroll
        for (int k = 1; k < D; ++k){
          if (k & 1) a1 = fmaf(mwO[k], rO[k], a1);
          else       a0 = fmaf(mwO[k], rO[k], a0);
        }
        Xe = a0 + a1; }
      float rE = rcpa(ex2(Xe) + 1.f);
      float yE = fmaf(-2.f, rE, 1.f);      // y[t]
      // neighbor step t (exact: Q[d] = C'[t,j]+h[t,j] from lane j)
      float rn[D];
      #pragma unroll
      for (int d = 0; d < D; ++d){
        float a0 = fmaf(mw2[d][0], r2[d][0], Q[d]), a1 = 0.f;
        #pragma unroll
        for (int k = 1; k < D; ++k){
          if (k & 1) a1 = fmaf(mw2[d][k], r2[d][k], a1);
          else       a0 = fmaf(mw2[d][k], r2[d][k], a0);
        }
        rn[d] = rcpa(ex2(a0 + a1) + 1.f);
      }
      // own odd step t+1 (uses locally computed neighbor r's)
      float Xo;
      { float a0 = fmaf(mwO[0], rn[0], xpre1), a1 = 0.f;
        #pragma unroll
        for (int k = 1; k < D; ++k){
          if (k & 1) a1 = fmaf(mwO[k], rn[k], a1);
          else       a0 = fmaf(mwO[k], rn[k], a0);
        }
        Xo = a0 + a1; }
      float rT1 = rcpa(ex2(Xo) + 1.f);
      float yO = fmaf(-2.f, rT1, 1.f);     // y[t+1]
      // IIR update2 (state -> t+2): yprev = y[t], yold = y[t-49]
      float yo49 = yhv[OFS + u2 + 1];
      A0n = fmaf(rh0, A0, fmaf(kp0, E0, ay0 * yE));
      E0 = fmaf(rh0, E0, ey0 * yE); A0 = A0n;
      A1n = fmaf(rh1, A1, fmaf(kp1, E1, ay1 * yE));
      E1 = fmaf(rh1, E1, ey1 * yE); A1 = A1n;
      A2n = fmaf(rh2, A2, fmaf(kp2, E2, fmaf(-cA, yo49, ay2 * yE)));
      E2 = fmaf(rh2, E2, fmaf(-cE, yo49, ey2 * yE)); A2 = A2n;
      xpreS = get9(c0, c1, p0, u2 + 2) + ((A0 + A1) + A2);   // Q source
      // gather round for next unit (r[t+1] and Q[t+2])
      int rb = __float_as_int(rT1);
      #pragma unroll
      for (int d = 0; d < D; ++d)
        rO[d] = __int_as_float(__builtin_amdgcn_ds_bpermute(madO[d], rb));
      #pragma unroll
      for (int d = 0; d < D; ++d)
        #pragma unroll
        for (int k = 0; k < D; ++k)
          r2[d][k] = __int_as_float(__builtin_amdgcn_ds_bpermute(mad2[d][k], rb));
      int qb = __float_as_int(xpreS);
      #pragma unroll
      for (int d = 0; d < D; ++d)
        Q[d] = __int_as_float(__builtin_amdgcn_ds_bpermute(madO[d], qb));
      // bookkeeping
      yhv[OFS + u2 + 50] = yE;
      yhv[OFS + u2 + 51] = yO;
      set8(ob0, ob1, u2,     fmaf(yE, wsub0, vo));
      set8(ob0, ob1, u2 + 1, fmaf(yO, wsub0, vo));
    }
    if (lane == 0 && tbase + 8 <= T_DATA){
      float4* q = (float4*)(yout + tbase);
      q[0] = ob0; q[1] = ob1;
    }
    tbase += 8;
  };

  using IC0 = std::integral_constant<int,0>;
  using IC8 = std::integral_constant<int,8>;
  if constexpr (D <= 4){
    #pragma unroll 1
    for (int ib = 0; ib < 1256; ++ib){       // 1256*16 = 20096
      block8(IC0{}, u0, u1, n0, n1);
      block8(IC8{}, n0, n1, u0, u1);
      #pragma unroll
      for (int j = 0; j < 50; ++j) yhv[j] = yhv[j + 16];
    }
  } else {
    #pragma unroll 1
    for (int ib = 0; ib < 1256; ++ib){
      block8(IC0{}, u0, u1, n0, n1);
      #pragma unroll
      for (int j = 0; j < 50; ++j) yhv[j] = yhv[j + 8];
      block8(IC0{}, n0, n1, u0, u1);
      #pragma unroll
      for (int j = 0; j < 50; ++j) yhv[j] = yhv[j + 8];
    }
  }
}

// ---------------- fallback single-step scan (KM=12), D > 6 ----------------
__global__ __launch_bounds__(64, 1) void k_scanfb(float* ws, float* yout){
  const int* wsi = (const int*)ws;
  if (wsi[OFF_PAR + 23] != 12) return;
  const int lane = threadIdx.x;
  const int s = lane < SUBU ? lane : SUBU - 1;
  constexpr int KM = 12;
  float mwp[KM]; int mad[KM];
  #pragma unroll
  for (int k = 0; k < KM; ++k){
    mwp[k] = ws[OFF_MW + s*KSTORE + k];
    mad[k] = wsi[OFF_MIDX + s*KSTORE + k] * 4;
  }
  const float* cc = ws + OFF_IIR + s*16;
  const float rh0 = cc[0],  kp0 = cc[1],  ay0 = cc[2],  ey0 = cc[3];
  const float rh1 = cc[4],  kp1 = cc[5],  ay1 = cc[6],  ey1 = cc[7];
  const float rh2 = cc[8],  kp2 = cc[9],  ay2 = cc[10], ey2 = cc[11];
  const float cA  = cc[12], cE  = cc[13];
  const float wsub0 = ws[OFF_PAR + SUBU];
  const float vo    = ws[OFF_PAR + SUBU + 1];
  const float* syncol = ws + OFF_SYN + s*TPAD;
  float yhv[66];
  #pragma unroll
  for (int j = 0; j < 66; ++j) yhv[j] = 0.f;
  float A0=0.f,E0=0.f,A1=0.f,E1=0.f,A2=0.f,E2=0.f;
  float pb[KM];
  #pragma unroll
  for (int k = 0; k < KM; ++k) pb[k] = 0.5f;
  float4 u0 = *(const float4*)(syncol + 0);
  float4 u1 = *(const float4*)(syncol + 4);
  float4 u2 = *(const float4*)(syncol + 8);
  float4 u3 = *(const float4*)(syncol + 12);
  float4 n0, n1, n2, n3;
  float xpre = u0.x;
  auto block16 = [&](int tbase, float4& b0, float4& b1, float4& b2, float4& b3,
                     float4& p0, float4& p1, float4& p2, float4& p3){
    const float4* src = (const float4*)(syncol + tbase + 16);
    p0 = src[0]; p1 = src[1]; p2 = src[2]; p3 = src[3];
    float4 ob0, ob1, ob2, ob3;
    #pragma unroll
    for (int u = 0; u < 16; ++u){
      float acc0 = fmaf(mwp[0], pb[0], xpre);
      float acc1 = mwp[1] * pb[1];
      #pragma unroll
      for (int k = 2; k + 1 < KM; k += 2){
        acc0 = fmaf(mwp[k],   pb[k],   acc0);
        acc1 = fmaf(mwp[k+1], pb[k+1], acc1);
      }
      float X  = acc0 + acc1;
      float r  = rcpa(ex2(X) + 1.f);
      int rb = __float_as_int(r);
      #pragma unroll
      for (int k = 0; k < KM; ++k)
        pb[k] = __int_as_float(__builtin_amdgcn_ds_bpermute(mad[k], rb));
      float y = fmaf(-2.f, r, 1.f);
      float yprev = yhv[u + 49];
      float yold  = yhv[u];
      float A0n = fmaf(rh0, A0, fmaf(kp0, E0, ay0 * yprev));
      E0 = fmaf(rh0, E0, ey0 * yprev); A0 = A0n;
      float A1n = fmaf(rh1, A1, fmaf(kp1, E1, ay1 * yprev));
      E1 = fmaf(rh1, E1, ey1 * yprev); A1 = A1n;
      float A2n = fmaf(rh2, A2, fmaf(kp2, E2, fmaf(-cA, yold, ay2 * yprev)));
      E2 = fmaf(rh2, E2, fmaf(-cE, yold, ey2 * yprev)); A2 = A2n;
      float h = (A0 + A1) + A2;
      float cn = (u < 15) ? get4(b0, b1, b2, b3, u + 1) : p0.x;
      xpre = cn + h;
      yhv[u + 50] = y;
      set4(ob0, ob1, ob2, ob3, u, fmaf(y, wsub0, vo));
    }
    #pragma unroll
    for (int j = 0; j < 50; ++j) yhv[j] = yhv[j + 16];
    if (lane == 0 && tbase + 16 <= T_DATA){
      float4* q = (float4*)(yout + tbase);
      q[0] = ob0; q[1] = ob1; q[2] = ob2; q[3] = ob3;
    }
  };
  #pragma unroll 1
  for (int ib = 0; ib < 628; ++ib){
    block16(ib*32,      u0, u1, u2, u3, n0, n1, n2, n3);
    block16(ib*32 + 16, n0, n1, n2, n3, u0, u1, u2, u3);
  }
}

// ---------------- epilogue: f32 Y -> output dtype --------------------------
__global__ __launch_bounds__(256) void k_out(const float* ws, void* outp){
  const int* wsi = (const int*)ws;
  const int bf = wsi[OFF_FLAG];
  int i = blockIdx.x * 256 + threadIdx.x;
  if (i < T_DATA){
    float v = ws[OFF_Y + i];
    if (bf) ((__hip_bfloat16*)outp)[i] = __float2bfloat16(v);
    else    ((float*)outp)[i] = v;
  }
}

// --------------------------------------------------------------------------
extern "C" void kernel_launch(void* const* d_in, const int* in_sizes, int n_in,
                              void* d_out, int out_size, void* d_ws, size_t ws_size,
                              hipStream_t stream){
  const void* S_e   = d_in[0];
  const void* S_i   = d_in[1];
  const void* C_den = d_in[2];
  const void* C_e   = d_in[3];
  const void* C_i   = d_in[4];
  const void* W_syn = d_in[5];
  const void* Tau_s = d_in[6];
  const void* D_syn = d_in[7];
  const void* W_hst = d_in[8];
  const void* Tau_h = d_in[9];
  const void* D_hst = d_in[10];
  const void* W_sub = d_in[11];
  const void* V_o   = d_in[12];
  const void* Theta = d_in[13];
  float* ws = (float*)d_ws;
  int* flagp = (int*)(ws + OFF_FLAG);

  k_detect<<<1, 256, 0, stream>>>(S_e, flagp);
  k_prep<<<1, 512, 0, stream>>>(C_den, W_syn, Tau_s, D_syn, W_hst, Tau_h, D_hst,
                                W_sub, V_o, Theta, ws);
  k_gemm<<<5000, 64, 0, stream>>>(S_e, C_e, E_NO, ws + OFF_INE, flagp);
  k_gemm<<<5000, 64, 0, stream>>>(S_i, C_i, I_NO, ws + OFF_INI, flagp);
  dim3 cgrid(79, 20);
  k_conv<<<cgrid, 256, 0, stream>>>(ws);
  float* yout = ws + OFF_Y;
  k_scan2<3><<<1, 64, 0, stream>>>(ws, yout);
  k_scan2<4><<<1, 64, 0, stream>>>(ws, yout);
  k_scan2<5><<<1, 64, 0, stream>>>(ws, yout);
  k_scan2<6><<<1, 64, 0, stream>>>(ws, yout);
  k_scanfb<<<1, 64, 0, stream>>>(ws, yout);
  k_out<<<79, 256, 0, stream>>>(ws, d_out);
}

// Round 6
// 2124.800 us; speedup vs baseline: 1.9215x; 1.9215x over previous
//
#include <hip/hip_runtime.h>
#include <hip/hip_bf16.h>
#include <stdint.h>
#include <type_traits>

#define SUBU 20
#define E_NO 2000
#define I_NO 500
#define T_DATA 20000
#define T_SYNK 200
#define HBAS 3
#define SBAS 3
#define TPAD 20096          // 1256 * 16

// workspace float offsets
#define OFF_SYN  0          // [20][TPAD]  c[s][t] = TK*(syn + theta + rowsum)
#define OFF_INE  401920     // [20][TPAD]
#define OFF_INI  803840     // [20][TPAD]  (reused as Y f32 by scan)
#define OFF_KE   1205760    // [20][200]
#define OFF_KI   1209760    // [20][200]
#define OFF_IIR  1213760    // [20][16] folded IIR consts (A-side TK-scaled)
#define OFF_MW   1214760    // [20][KSTORE]  mwp = -2*TK*m
#define OFF_MIDX 1215000    // [20][KSTORE] ints
#define OFF_PAR  1215240    // TK*(theta+rowsum)[20], wsub0, vo, ksel(int at +23)
#define OFF_FLAG 1215264    // int bf16 flag
#define OFF_Y    OFF_INI
#define KSTORE   12

#define TKC 2.8853900817779268f   // 2*log2(e)

__device__ __forceinline__ float bf2f(unsigned short u){
  unsigned v = ((unsigned)u) << 16; float f; __builtin_memcpy(&f, &v, 4); return f;
}
__device__ __forceinline__ float ldany(const void* p, int i, int bf){
  return bf ? bf2f(((const unsigned short*)p)[i]) : ((const float*)p)[i];
}
__device__ __forceinline__ float ex2(float x){ return __builtin_amdgcn_exp2f(x); }
__device__ __forceinline__ float rcpa(float x){ return __builtin_amdgcn_rcpf(x); }

// ------- prep (with fused dtype detection): kernels, IIR, tables, params --
__global__ __launch_bounds__(512) void k_prep(
    const void* Se, const void* Cden, const void* Wsyn, const void* Tausyn,
    const void* Dsyn, const void* Whist, const void* Tauhist, const void* Dhist,
    const void* Wsub, const void* Vo, const void* Theta, float* ws){
  int* wsi = (int*)ws;
  const int tx = threadIdx.x;
  __shared__ int found, mx;
  if (tx == 0){ found = 0; mx = 0; }
  __syncthreads();
  // dtype detect: S_e is exactly {0,1}; bf16 1.0 patterns in raw words
  {
    const unsigned* w = (const unsigned*)Se;
    int hit = 0;
    for (int i = tx; i < 8192; i += 512){
      unsigned x = w[i];
      if (x == 0x00003F80u || x == 0x3F803F80u) hit = 1;
    }
    if (hit) atomicOr(&found, 1);
  }
  __syncthreads();
  const int bf = found;
  if (tx == 0) wsi[OFF_FLAG] = bf;
  // synaptic kernels ke/ki [20][200]
  for (int idx = tx; idx < SUBU * T_SYNK; idx += 512){
    int s = idx / T_SYNK, t = idx % T_SYNK;
    for (int c = 0; c < 2; ++c){
      float delta = __expf(ldany(Dsyn, s*2 + c, bf));
      float acc = 0.f;
      for (int b = 0; b < SBAS; ++b){
        float tau = __expf(ldany(Tausyn, b*2 + c, bf));
        float w   = ldany(Wsyn, (s*SBAS + b)*2 + c, bf);
        float tt  = fmaxf((float)t - delta, 0.f) / tau;
        acc += w * tt * __expf(-tt);
      }
      ws[(c == 0 ? OFF_KE : OFF_KI) + s*T_SYNK + t] = acc;
    }
  }
  // folded per-lane IIR constants; A-side carries TK*w
  if (tx < SUBU * HBAS){
    int s = tx / HBAS, b = tx % HBAS;
    float tau = __expf(ldany(Tauhist, b, bf));
    float w   = TKC * ldany(Whist, s*HBAS + b, bf);
    float dl  = ldany(Dhist, s, bf);
    float rho = __expf(-1.f / tau);
    float e1  = __expf(-(1.f - dl) / tau);
    float g1  = ((1.f - dl) / tau) * e1;
    float kap = rho / tau;
    float* c = ws + OFF_IIR + s*16 + b*4;
    c[0] = rho;          // decay
    c[1] = w * kap;      // E -> A  (TK-scaled)
    c[2] = w * g1;       // y_new coeff into A (TK-scaled)
    c[3] = e1;           // y_new coeff into E (unscaled)
    if (b == 2){
      float e49 = __expf(-(49.f - dl) / tau);
      float g49 = ((49.f - dl) / tau) * e49;
      ws[OFF_IIR + s*16 + 12] = w * (rho*g49 + kap*e49);  // cA (TK-scaled)
      ws[OFF_IIR + s*16 + 13] = rho * e49;                // cE (unscaled)
    }
  }
  // sparse gather weights mwp = -2*TK*C_den*W_sub ; rowsum fold into PAR
  if (tx < SUBU){
    int s = tx, cnt = 0;
    float rowsum = 0.f;
    for (int sp = 0; sp < SUBU; ++sp){
      float c = ldany(Cden, s*SUBU + sp, bf);
      if (c != 0.f && cnt < KSTORE){
        float m = c * ldany(Wsub, sp, bf);
        rowsum += m;
        ws[OFF_MW + s*KSTORE + cnt]  = -2.f * TKC * m;
        wsi[OFF_MIDX + s*KSTORE + cnt] = sp;
        ++cnt;
      }
    }
    for (int k = cnt; k < KSTORE; ++k){
      ws[OFF_MW + s*KSTORE + k] = 0.f; wsi[OFF_MIDX + s*KSTORE + k] = 0;
    }
    atomicMax(&mx, cnt);
    ws[OFF_PAR + s] = TKC * (ldany(Theta, s, bf) + rowsum);
  }
  __syncthreads();
  if (tx == 0){
    ws[OFF_PAR + SUBU]     = ldany(Wsub, 0, bf);
    ws[OFF_PAR + SUBU + 1] = ldany(Vo, 0, bf);
    wsi[OFF_PAR + 23] = (mx <= 3) ? 3 : (mx <= 4 ? 4 : (mx <= 6 ? 6 : 12));
  }
}

// ------- skinny GEMM (4 waves/block): in_T[s][t] = sum_e S[t][e]*C[s][e] --
template<int BF>
__device__ __forceinline__ void gemm_impl(const void* S, const void* C, int W,
                                          float* dst, int t0, int lane){
  float acc[4][SUBU];
  #pragma unroll
  for (int r = 0; r < 4; ++r)
    #pragma unroll
    for (int s = 0; s < SUBU; ++s) acc[r][s] = 0.f;
  for (int e = lane; e < W; e += 64){
    float s0 = ldany(S, (t0+0)*W + e, BF);
    float s1 = ldany(S, (t0+1)*W + e, BF);
    float s2 = ldany(S, (t0+2)*W + e, BF);
    float s3 = ldany(S, (t0+3)*W + e, BF);
    #pragma unroll
    for (int s = 0; s < SUBU; ++s){
      float c = ldany(C, s*W + e, BF);
      acc[0][s] = fmaf(s0, c, acc[0][s]);
      acc[1][s] = fmaf(s1, c, acc[1][s]);
      acc[2][s] = fmaf(s2, c, acc[2][s]);
      acc[3][s] = fmaf(s3, c, acc[3][s]);
    }
  }
  #pragma unroll
  for (int r = 0; r < 4; ++r){
    #pragma unroll
    for (int s = 0; s < SUBU; ++s){
      float v = acc[r][s];
      #pragma unroll
      for (int m = 32; m >= 1; m >>= 1) v += __shfl_xor(v, m, 64);
      if (lane == 0) dst[s*TPAD + t0 + r] = v;
    }
  }
}

__global__ __launch_bounds__(256) void k_gemm(const void* S, const void* C, int W,
                                              float* dst, const int* flagp){
  const int wave = threadIdx.x >> 6, lane = threadIdx.x & 63;
  const int t0 = blockIdx.x * 16 + wave * 4;
  if (*flagp) gemm_impl<1>(S, C, W, dst, t0, lane);
  else        gemm_impl<0>(S, C, W, dst, t0, lane);
}

// ------- causal conv (+theta/rowsum fold, TK scale): c[s][t] --------------
__global__ __launch_bounds__(256) void k_conv(float* ws){
  const int s  = blockIdx.y;
  const int t0 = blockIdx.x * 256;
  const float* ine = ws + OFF_INE + s*TPAD;
  const float* ini = ws + OFF_INI + s*TPAD;
  __shared__ float eL[455], iL[455], keL[T_SYNK], kiL[T_SYNK];
  for (int j = threadIdx.x; j < 455; j += 256){
    int t = t0 - 199 + j;
    bool ok = (t >= 0 && t < TPAD);
    eL[j] = ok ? ine[t] : 0.f;
    iL[j] = ok ? ini[t] : 0.f;
  }
  for (int j = threadIdx.x; j < T_SYNK; j += 256){
    keL[j] = ws[OFF_KE + s*T_SYNK + j];
    kiL[j] = ws[OFF_KI + s*T_SYNK + j];
  }
  __syncthreads();
  int t = t0 + threadIdx.x;
  if (t < TPAD){
    float a0 = 0.f, a1 = 0.f;
    #pragma unroll 4
    for (int k = 0; k < T_SYNK; ++k){
      a0 = fmaf(keL[k], eL[threadIdx.x + 199 - k], a0);
      a1 = fmaf(kiL[k], iL[threadIdx.x + 199 - k], a1);
    }
    ws[OFF_SYN + s*TPAD + t] = fmaf(TKC, a0 + a1, ws[OFF_PAR + s]);
  }
}

// ------- static float4 component helpers ----------------------------------
__device__ __forceinline__ float get4(const float4& a, const float4& b,
                                      const float4& c, const float4& d, int u){
  const float4& q = (u < 4) ? a : ((u < 8) ? b : ((u < 12) ? c : d));
  int r = u & 3;
  return (r == 0) ? q.x : ((r == 1) ? q.y : ((r == 2) ? q.z : q.w));
}
__device__ __forceinline__ void set4(float4& a, float4& b, float4& c, float4& d,
                                     int u, float v){
  float4& q = (u < 4) ? a : ((u < 8) ? b : ((u < 12) ? c : d));
  int r = u & 3;
  if (r == 0) q.x = v; else if (r == 1) q.y = v; else if (r == 2) q.z = v; else q.w = v;
}

// ------- sequential scan: 1 wave, r-gather bpermute, r-form IIR -----------
template<int KM>
__global__ __launch_bounds__(64, 1) void k_scan(float* ws, float* yout){
  const int* wsi = (const int*)ws;
  if (wsi[OFF_PAR + 23] != KM) return;
  const int lane = threadIdx.x;
  const int s = lane < SUBU ? lane : SUBU - 1;
  float mwp[KM]; int mad[KM];
  #pragma unroll
  for (int k = 0; k < KM; ++k){
    mwp[k] = ws[OFF_MW + s*KSTORE + k];
    mad[k] = wsi[OFF_MIDX + s*KSTORE + k] * 4;
  }
  const float* cc = ws + OFF_IIR + s*16;
  // r-form constants: y = 1 - 2r folded; drive at r=0.5 is exactly 0
  const float rh0 = cc[0], kp0 = cc[1], ayc0 = cc[2], eyc0 = cc[3];
  const float rh1 = cc[4], kp1 = cc[5], ayc1 = cc[6], eyc1 = cc[7];
  const float rh2 = cc[8], kp2 = cc[9];
  const float cA = cc[12], cE = cc[13];
  const float ayr0 = -2.f*ayc0, eyr0 = -2.f*eyc0;
  const float ayr1 = -2.f*ayc1, eyr1 = -2.f*eyc1;
  const float ayr2 = -2.f*cc[10], eyr2 = -2.f*cc[11];
  const float cAr = 2.f*cA, cEr = 2.f*cE;
  const float c2A = cc[10] - cA;     // (ay2 - cA) combined constant
  const float c2E = cc[11] - cE;     // (ey2 - cE)
  const float wsub0 = ws[OFF_PAR + SUBU];
  const float vo    = ws[OFF_PAR + SUBU + 1];
  const float m2w = -2.f * wsub0, wvo = wsub0 + vo;
  const float* syncol = ws + OFF_SYN + s*TPAD;

  float rhv[82];                      // r history: rhv[OFS+u] = r[t-50]
  #pragma unroll
  for (int j = 0; j < 82; ++j) rhv[j] = 0.5f;
  float A0=0.f,E0=0.f,A1=0.f,E1=0.f,A2=0.f,E2=0.f;
  float pb[KM];
  #pragma unroll
  for (int k = 0; k < KM; ++k) pb[k] = 0.5f;
  float4 u0 = *(const float4*)(syncol + 0);
  float4 u1 = *(const float4*)(syncol + 4);
  float4 u2 = *(const float4*)(syncol + 8);
  float4 u3 = *(const float4*)(syncol + 12);
  float4 n0, n1, n2, n3;
  float xpre = u0.x;                  // X[0] partial (h = 0)

  auto block16 = [&](auto OFS_, int tbase, float4& b0, float4& b1, float4& b2,
                     float4& b3, float4& p0, float4& p1, float4& p2, float4& p3){
    constexpr int OFS = decltype(OFS_)::value;
    const float4* src = (const float4*)(syncol + tbase + 16);
    p0 = src[0]; p1 = src[1]; p2 = src[2]; p3 = src[3];
    float4 ob0, ob1, ob2, ob3;
    #pragma unroll
    for (int u = 0; u < 16; ++u){
      // X[t] = xpre + sum_k mwp[k]*r_gathered[k]
      float acc0 = fmaf(mwp[0], pb[0], xpre);
      float acc1 = mwp[1] * pb[1];
      #pragma unroll
      for (int k = 2; k < KM; ++k){
        if (k & 1) acc1 = fmaf(mwp[k], pb[k], acc1);
        else       acc0 = fmaf(mwp[k], pb[k], acc0);
      }
      float X  = acc0 + acc1;
      float r  = rcpa(ex2(X) + 1.f);
      // issue next gathers ASAP; remainder runs in DS shadow
      int rb = __float_as_int(r);
      #pragma unroll
      for (int k = 0; k < KM; ++k)
        pb[k] = __int_as_float(__builtin_amdgcn_ds_bpermute(mad[k], rb));
      float rp = rhv[OFS + u + 49];          // r[t-1]
      float ro = rhv[OFS + u];               // r[t-50]
      // r-form folded IIR -> h[t+1]
      float A0n = fmaf(rh0, A0, fmaf(kp0, E0, fmaf(ayr0, rp, ayc0)));
      E0 = fmaf(rh0, E0, fmaf(eyr0, rp, eyc0)); A0 = A0n;
      float A1n = fmaf(rh1, A1, fmaf(kp1, E1, fmaf(ayr1, rp, ayc1)));
      E1 = fmaf(rh1, E1, fmaf(eyr1, rp, eyc1)); A1 = A1n;
      float A2n = fmaf(rh2, A2, fmaf(kp2, E2, fmaf(ayr2, rp, fmaf(cAr, ro, c2A))));
      E2 = fmaf(rh2, E2, fmaf(eyr2, rp, fmaf(cEr, ro, c2E))); A2 = A2n;
      float h = (A0 + A1) + A2;
      float cn = (u < 15) ? get4(b0, b1, b2, b3, u + 1) : p0.x;
      xpre = cn + h;
      rhv[OFS + u + 50] = r;
      set4(ob0, ob1, ob2, ob3, u, fmaf(r, m2w, wvo));
    }
    if (lane == 0 && tbase + 16 <= T_DATA){
      float4* q = (float4*)(yout + tbase);
      q[0] = ob0; q[1] = ob1; q[2] = ob2; q[3] = ob3;
    }
  };

  using IC0  = std::integral_constant<int,0>;
  using IC16 = std::integral_constant<int,16>;
  #pragma unroll 1
  for (int ib = 0; ib < 628; ++ib){          // 628*32 = 20096 steps
    block16(IC0{},  ib*32,      u0, u1, u2, u3, n0, n1, n2, n3);
    block16(IC16{}, ib*32 + 16, n0, n1, n2, n3, u0, u1, u2, u3);
    #pragma unroll
    for (int j = 0; j < 50; ++j) rhv[j] = rhv[j + 32];
  }
}

// ------- epilogue: f32 Y -> output dtype ----------------------------------
__global__ __launch_bounds__(256) void k_out(const float* ws, void* outp){
  const int* wsi = (const int*)ws;
  const int bf = wsi[OFF_FLAG];
  int i = blockIdx.x * 256 + threadIdx.x;
  if (i < T_DATA){
    float v = ws[OFF_Y + i];
    if (bf) ((__hip_bfloat16*)outp)[i] = __float2bfloat16(v);
    else    ((float*)outp)[i] = v;
  }
}

// --------------------------------------------------------------------------
extern "C" void kernel_launch(void* const* d_in, const int* in_sizes, int n_in,
                              void* d_out, int out_size, void* d_ws, size_t ws_size,
                              hipStream_t stream){
  const void* S_e   = d_in[0];
  const void* S_i   = d_in[1];
  const void* C_den = d_in[2];
  const void* C_e   = d_in[3];
  const void* C_i   = d_in[4];
  const void* W_syn = d_in[5];
  const void* Tau_s = d_in[6];
  const void* D_syn = d_in[7];
  const void* W_hst = d_in[8];
  const void* Tau_h = d_in[9];
  const void* D_hst = d_in[10];
  const void* W_sub = d_in[11];
  const void* V_o   = d_in[12];
  const void* Theta = d_in[13];
  float* ws = (float*)d_ws;
  int* flagp = (int*)(ws + OFF_FLAG);

  k_prep<<<1, 512, 0, stream>>>(S_e, C_den, W_syn, Tau_s, D_syn, W_hst, Tau_h,
                                D_hst, W_sub, V_o, Theta, ws);
  k_gemm<<<1250, 256, 0, stream>>>(S_e, C_e, E_NO, ws + OFF_INE, flagp);
  k_gemm<<<1250, 256, 0, stream>>>(S_i, C_i, I_NO, ws + OFF_INI, flagp);
  dim3 cgrid(79, 20);
  k_conv<<<cgrid, 256, 0, stream>>>(ws);
  float* yout = ws + OFF_Y;
  k_scan<3><<<1, 64, 0, stream>>>(ws, yout);
  k_scan<4><<<1, 64, 0, stream>>>(ws, yout);
  k_scan<6><<<1, 64, 0, stream>>>(ws, yout);
  k_scan<12><<<1, 64, 0, stream>>>(ws, yout);
  k_out<<<79, 256, 0, stream>>>(ws, d_out);
}

// Round 7
// 1994.895 us; speedup vs baseline: 2.0466x; 1.0651x over previous
//
#include <hip/hip_runtime.h>
#include <hip/hip_bf16.h>
#include <stdint.h>
#include <type_traits>

#define SUBU 20
#define E_NO 2000
#define I_NO 500
#define T_DATA 20000
#define T_SYNK 200
#define HBAS 3
#define SBAS 3
#define TPAD 20096          // 1256 * 16

// workspace float offsets
#define OFF_SYN  0          // [20][TPAD]  c[s][t] = TK*(syn + theta + rowsum)
#define OFF_INE  401920     // [20][TPAD]
#define OFF_INI  803840     // [20][TPAD]  (reused as Y f32 by scan)
#define OFF_KE   1205760    // [20][200]
#define OFF_KI   1209760    // [20][200]
#define OFF_IIR  1213760    // [20][16] folded IIR consts (A-side TK-scaled)
#define OFF_MW   1214760    // [20][KSTORE]  mwp = -2*TK*m
#define OFF_MIDX 1215000    // [20][KSTORE] ints
#define OFF_PAR  1215240    // TK*(theta+rowsum)[20], wsub0, vo, ksel(int at +23)
#define OFF_FLAG 1215264    // int bf16 flag
#define OFF_Y    OFF_INI
#define KSTORE   12

#define TKC 2.8853900817779268f   // 2*log2(e)

__device__ __forceinline__ float bf2f(unsigned short u){
  unsigned v = ((unsigned)u) << 16; float f; __builtin_memcpy(&f, &v, 4); return f;
}
__device__ __forceinline__ float ldany(const void* p, int i, int bf){
  return bf ? bf2f(((const unsigned short*)p)[i]) : ((const float*)p)[i];
}
__device__ __forceinline__ float ex2(float x){ return __builtin_amdgcn_exp2f(x); }
__device__ __forceinline__ float rcpa(float x){ return __builtin_amdgcn_rcpf(x); }

// ------- prep (with fused dtype detection): kernels, IIR, tables, params --
__global__ __launch_bounds__(512) void k_prep(
    const void* Se, const void* Cden, const void* Wsyn, const void* Tausyn,
    const void* Dsyn, const void* Whist, const void* Tauhist, const void* Dhist,
    const void* Wsub, const void* Vo, const void* Theta, float* ws){
  int* wsi = (int*)ws;
  const int tx = threadIdx.x;
  __shared__ int found, mx;
  if (tx == 0){ found = 0; mx = 0; }
  __syncthreads();
  // dtype detect: S_e is exactly {0,1}; bf16 1.0 patterns in raw words
  {
    const unsigned* w = (const unsigned*)Se;
    int hit = 0;
    for (int i = tx; i < 8192; i += 512){
      unsigned x = w[i];
      if (x == 0x00003F80u || x == 0x3F803F80u) hit = 1;
    }
    if (hit) atomicOr(&found, 1);
  }
  __syncthreads();
  const int bf = found;
  if (tx == 0) wsi[OFF_FLAG] = bf;
  // synaptic kernels ke/ki [20][200]
  for (int idx = tx; idx < SUBU * T_SYNK; idx += 512){
    int s = idx / T_SYNK, t = idx % T_SYNK;
    for (int c = 0; c < 2; ++c){
      float delta = __expf(ldany(Dsyn, s*2 + c, bf));
      float acc = 0.f;
      for (int b = 0; b < SBAS; ++b){
        float tau = __expf(ldany(Tausyn, b*2 + c, bf));
        float w   = ldany(Wsyn, (s*SBAS + b)*2 + c, bf);
        float tt  = fmaxf((float)t - delta, 0.f) / tau;
        acc += w * tt * __expf(-tt);
      }
      ws[(c == 0 ? OFF_KE : OFF_KI) + s*T_SYNK + t] = acc;
    }
  }
  // folded per-lane IIR constants; A-side carries TK*w
  if (tx < SUBU * HBAS){
    int s = tx / HBAS, b = tx % HBAS;
    float tau = __expf(ldany(Tauhist, b, bf));
    float w   = TKC * ldany(Whist, s*HBAS + b, bf);
    float dl  = ldany(Dhist, s, bf);
    float rho = __expf(-1.f / tau);
    float e1  = __expf(-(1.f - dl) / tau);
    float g1  = ((1.f - dl) / tau) * e1;
    float kap = rho / tau;
    float* c = ws + OFF_IIR + s*16 + b*4;
    c[0] = rho;          // decay
    c[1] = w * kap;      // E -> A  (TK-scaled)
    c[2] = w * g1;       // y_new coeff into A (TK-scaled)
    c[3] = e1;           // y_new coeff into E (unscaled)
    if (b == 2){
      float e49 = __expf(-(49.f - dl) / tau);
      float g49 = ((49.f - dl) / tau) * e49;
      ws[OFF_IIR + s*16 + 12] = w * (rho*g49 + kap*e49);  // cA (TK-scaled)
      ws[OFF_IIR + s*16 + 13] = rho * e49;                // cE (unscaled)
    }
  }
  // sparse gather weights mwp = -2*TK*C_den*W_sub ; rowsum fold into PAR
  if (tx < SUBU){
    int s = tx, cnt = 0;
    float rowsum = 0.f;
    for (int sp = 0; sp < SUBU; ++sp){
      float c = ldany(Cden, s*SUBU + sp, bf);
      if (c != 0.f && cnt < KSTORE){
        float m = c * ldany(Wsub, sp, bf);
        rowsum += m;
        ws[OFF_MW + s*KSTORE + cnt]  = -2.f * TKC * m;
        wsi[OFF_MIDX + s*KSTORE + cnt] = sp;
        ++cnt;
      }
    }
    for (int k = cnt; k < KSTORE; ++k){
      ws[OFF_MW + s*KSTORE + k] = 0.f; wsi[OFF_MIDX + s*KSTORE + k] = 0;
    }
    atomicMax(&mx, cnt);
    ws[OFF_PAR + s] = TKC * (ldany(Theta, s, bf) + rowsum);
  }
  __syncthreads();
  if (tx == 0){
    ws[OFF_PAR + SUBU]     = ldany(Wsub, 0, bf);
    ws[OFF_PAR + SUBU + 1] = ldany(Vo, 0, bf);
    wsi[OFF_PAR + 23] = (mx <= 3) ? 3 : (mx <= 4 ? 4 : (mx <= 5 ? 5 :
                        (mx <= 6 ? 6 : 12)));
  }
}

// ------- skinny GEMM (4 waves/block): in_T[s][t] = sum_e S[t][e]*C[s][e] --
template<int BF>
__device__ __forceinline__ void gemm_impl(const void* S, const void* C, int W,
                                          float* dst, int t0, int lane){
  float acc[4][SUBU];
  #pragma unroll
  for (int r = 0; r < 4; ++r)
    #pragma unroll
    for (int s = 0; s < SUBU; ++s) acc[r][s] = 0.f;
  for (int e = lane; e < W; e += 64){
    float s0 = ldany(S, (t0+0)*W + e, BF);
    float s1 = ldany(S, (t0+1)*W + e, BF);
    float s2 = ldany(S, (t0+2)*W + e, BF);
    float s3 = ldany(S, (t0+3)*W + e, BF);
    #pragma unroll
    for (int s = 0; s < SUBU; ++s){
      float c = ldany(C, s*W + e, BF);
      acc[0][s] = fmaf(s0, c, acc[0][s]);
      acc[1][s] = fmaf(s1, c, acc[1][s]);
      acc[2][s] = fmaf(s2, c, acc[2][s]);
      acc[3][s] = fmaf(s3, c, acc[3][s]);
    }
  }
  #pragma unroll
  for (int r = 0; r < 4; ++r){
    #pragma unroll
    for (int s = 0; s < SUBU; ++s){
      float v = acc[r][s];
      #pragma unroll
      for (int m = 32; m >= 1; m >>= 1) v += __shfl_xor(v, m, 64);
      if (lane == 0) dst[s*TPAD + t0 + r] = v;
    }
  }
}

__global__ __launch_bounds__(256) void k_gemm(const void* S, const void* C, int W,
                                              float* dst, const int* flagp){
  const int wave = threadIdx.x >> 6, lane = threadIdx.x & 63;
  const int t0 = blockIdx.x * 16 + wave * 4;
  if (*flagp) gemm_impl<1>(S, C, W, dst, t0, lane);
  else        gemm_impl<0>(S, C, W, dst, t0, lane);
}

// ------- causal conv (+theta/rowsum fold, TK scale): c[s][t] --------------
__global__ __launch_bounds__(256) void k_conv(float* ws){
  const int s  = blockIdx.y;
  const int t0 = blockIdx.x * 256;
  const float* ine = ws + OFF_INE + s*TPAD;
  const float* ini = ws + OFF_INI + s*TPAD;
  __shared__ float eL[455], iL[455], keL[T_SYNK], kiL[T_SYNK];
  for (int j = threadIdx.x; j < 455; j += 256){
    int t = t0 - 199 + j;
    bool ok = (t >= 0 && t < TPAD);
    eL[j] = ok ? ine[t] : 0.f;
    iL[j] = ok ? ini[t] : 0.f;
  }
  for (int j = threadIdx.x; j < T_SYNK; j += 256){
    keL[j] = ws[OFF_KE + s*T_SYNK + j];
    kiL[j] = ws[OFF_KI + s*T_SYNK + j];
  }
  __syncthreads();
  int t = t0 + threadIdx.x;
  if (t < TPAD){
    float a0 = 0.f, a1 = 0.f;
    #pragma unroll 4
    for (int k = 0; k < T_SYNK; ++k){
      a0 = fmaf(keL[k], eL[threadIdx.x + 199 - k], a0);
      a1 = fmaf(kiL[k], iL[threadIdx.x + 199 - k], a1);
    }
    ws[OFF_SYN + s*TPAD + t] = fmaf(TKC, a0 + a1, ws[OFF_PAR + s]);
  }
}

// ------- static float4 component helpers ----------------------------------
__device__ __forceinline__ float get4(const float4& a, const float4& b,
                                      const float4& c, const float4& d, int u){
  const float4& q = (u < 4) ? a : ((u < 8) ? b : ((u < 12) ? c : d));
  int r = u & 3;
  return (r == 0) ? q.x : ((r == 1) ? q.y : ((r == 2) ? q.z : q.w));
}
__device__ __forceinline__ void set4(float4& a, float4& b, float4& c, float4& d,
                                     int u, float v){
  float4& q = (u < 4) ? a : ((u < 8) ? b : ((u < 12) ? c : d));
  int r = u & 3;
  if (r == 0) q.x = v; else if (r == 1) q.y = v; else if (r == 2) q.z = v; else q.w = v;
}

// ------- sequential scan: 1 wave, r-gather bpermute, LDS ring for y[t-50] -
// Ring: per-lane private 64-entry row (stride 68 floats -> 16B aligned,
// 2-way bank alias only). Phase-specialized static offsets (PH in 0/16/32/48).
template<int KM>
__global__ __launch_bounds__(64, 1) void k_scan(float* ws, float* yout){
  const int* wsi = (const int*)ws;
  if (wsi[OFF_PAR + 23] != KM) return;
  __shared__ float ring[64*68];
  const int lane = threadIdx.x;
  const int s = lane < SUBU ? lane : SUBU - 1;
  float* rbase = &ring[lane*68];
  {
    float4 z = make_float4(0.f, 0.f, 0.f, 0.f);
    float4* rq = (float4*)rbase;
    #pragma unroll
    for (int j = 0; j < 16; ++j) rq[j] = z;     // zero 64 entries
  }
  float mwp[KM]; int mad[KM];
  #pragma unroll
  for (int k = 0; k < KM; ++k){
    mwp[k] = ws[OFF_MW + s*KSTORE + k];
    mad[k] = wsi[OFF_MIDX + s*KSTORE + k] * 4;
  }
  const float* cc = ws + OFF_IIR + s*16;
  const float rh0 = cc[0],  kp0 = cc[1],  ay0 = cc[2],  ey0 = cc[3];
  const float rh1 = cc[4],  kp1 = cc[5],  ay1 = cc[6],  ey1 = cc[7];
  const float rh2 = cc[8],  kp2 = cc[9],  ay2 = cc[10], ey2 = cc[11];
  const float cA  = cc[12], cE  = cc[13];
  const float wsub0 = ws[OFF_PAR + SUBU];
  const float vo    = ws[OFF_PAR + SUBU + 1];
  const float* syncol = ws + OFF_SYN + s*TPAD;

  float A0=0.f,E0=0.f,A1=0.f,E1=0.f,A2=0.f,E2=0.f;
  float pb[KM];
  #pragma unroll
  for (int k = 0; k < KM; ++k) pb[k] = 0.5f;    // r for y=0
  float yprev = 0.f;                            // y[t-1]
  float roN   = 0.f;                            // y[t-50] for current step
  float4 u0 = *(const float4*)(syncol + 0);
  float4 u1 = *(const float4*)(syncol + 4);
  float4 u2 = *(const float4*)(syncol + 8);
  float4 u3 = *(const float4*)(syncol + 12);
  float4 n0, n1, n2, n3;
  float xpre = u0.x;                            // X[0] partial (h = 0)

  auto block16 = [&](auto PH_, int tbase, float4& b0, float4& b1, float4& b2,
                     float4& b3, float4& p0, float4& p1, float4& p2, float4& p3){
    constexpr int PH = decltype(PH_)::value;    // ring phase = tbase & 63
    const float4* src = (const float4*)(syncol + tbase + 16);
    p0 = src[0]; p1 = src[1]; p2 = src[2]; p3 = src[3];
    float4 ob0, ob1, ob2, ob3;
    #pragma unroll
    for (int u = 0; u < 16; ++u){
      // X[t] = xpre + sum_k mwp[k]*r_gathered[k]   (mwp = -2*TK*m)
      float acc0 = fmaf(mwp[0], pb[0], xpre);
      float acc1 = mwp[1] * pb[1];
      #pragma unroll
      for (int k = 2; k < KM; ++k){
        if (k & 1) acc1 = fmaf(mwp[k], pb[k], acc1);
        else       acc0 = fmaf(mwp[k], pb[k], acc0);
      }
      float X  = acc0 + acc1;
      float r  = rcpa(ex2(X) + 1.f);
      // critical: issue next-step gathers immediately
      int rb = __float_as_int(r);
      #pragma unroll
      for (int k = 0; k < KM; ++k)
        pb[k] = __int_as_float(__builtin_amdgcn_ds_bpermute(mad[k], rb));
      float y = fmaf(-2.f, r, 1.f);             // y[t]
      float ro = roN;                           // y[t-50] (prefetched)
      // folded IIR -> h[t+1]; input tap is y[t-1]
      float A0n = fmaf(rh0, A0, fmaf(kp0, E0, ay0 * yprev));
      E0 = fmaf(rh0, E0, ey0 * yprev); A0 = A0n;
      float A1n = fmaf(rh1, A1, fmaf(kp1, E1, ay1 * yprev));
      E1 = fmaf(rh1, E1, ey1 * yprev); A1 = A1n;
      float A2n = fmaf(rh2, A2, fmaf(kp2, E2, fmaf(-cA, ro, ay2 * yprev)));
      E2 = fmaf(rh2, E2, fmaf(-cE, ro, ey2 * yprev)); A2 = A2n;
      float h = (A0 + A1) + A2;
      float cn = (u < 15) ? get4(b0, b1, b2, b3, u + 1) : p0.x;
      xpre = cn + h;
      // ring ops (static offsets; latency hidden behind bpermute round)
      rbase[PH + u] = y;                        // write y[t] at (t & 63)
      roN = rbase[(PH + u + 15) & 63];          // read y[t-49] for step t+1
      yprev = y;
      set4(ob0, ob1, ob2, ob3, u, fmaf(y, wsub0, vo));
    }
    if (lane == 0 && tbase + 16 <= T_DATA){
      float4* q = (float4*)(yout + tbase);
      q[0] = ob0; q[1] = ob1; q[2] = ob2; q[3] = ob3;
    }
  };

  using P0  = std::integral_constant<int,0>;
  using P16 = std::integral_constant<int,16>;
  using P32 = std::integral_constant<int,32>;
  using P48 = std::integral_constant<int,48>;
  #pragma unroll 1
  for (int ib2 = 0; ib2 < 314; ++ib2){          // 314*64 = 20096 steps
    const int tb = ib2 * 64;
    block16(P0{},  tb,      u0, u1, u2, u3, n0, n1, n2, n3);
    block16(P16{}, tb + 16, n0, n1, n2, n3, u0, u1, u2, u3);
    block16(P32{}, tb + 32, u0, u1, u2, u3, n0, n1, n2, n3);
    block16(P48{}, tb + 48, n0, n1, n2, n3, u0, u1, u2, u3);
  }
}

// ------- epilogue: f32 Y -> output dtype ----------------------------------
__global__ __launch_bounds__(256) void k_out(const float* ws, void* outp){
  const int* wsi = (const int*)ws;
  const int bf = wsi[OFF_FLAG];
  int i = blockIdx.x * 256 + threadIdx.x;
  if (i < T_DATA){
    float v = ws[OFF_Y + i];
    if (bf) ((__hip_bfloat16*)outp)[i] = __float2bfloat16(v);
    else    ((float*)outp)[i] = v;
  }
}

// --------------------------------------------------------------------------
extern "C" void kernel_launch(void* const* d_in, const int* in_sizes, int n_in,
                              void* d_out, int out_size, void* d_ws, size_t ws_size,
                              hipStream_t stream){
  const void* S_e   = d_in[0];
  const void* S_i   = d_in[1];
  const void* C_den = d_in[2];
  const void* C_e   = d_in[3];
  const void* C_i   = d_in[4];
  const void* W_syn = d_in[5];
  const void* Tau_s = d_in[6];
  const void* D_syn = d_in[7];
  const void* W_hst = d_in[8];
  const void* Tau_h = d_in[9];
  const void* D_hst = d_in[10];
  const void* W_sub = d_in[11];
  const void* V_o   = d_in[12];
  const void* Theta = d_in[13];
  float* ws = (float*)d_ws;
  int* flagp = (int*)(ws + OFF_FLAG);

  k_prep<<<1, 512, 0, stream>>>(S_e, C_den, W_syn, Tau_s, D_syn, W_hst, Tau_h,
                                D_hst, W_sub, V_o, Theta, ws);
  k_gemm<<<1250, 256, 0, stream>>>(S_e, C_e, E_NO, ws + OFF_INE, flagp);
  k_gemm<<<1250, 256, 0, stream>>>(S_i, C_i, I_NO, ws + OFF_INI, flagp);
  dim3 cgrid(79, 20);
  k_conv<<<cgrid, 256, 0, stream>>>(ws);
  float* yout = ws + OFF_Y;
  k_scan<3><<<1, 64, 0, stream>>>(ws, yout);
  k_scan<4><<<1, 64, 0, stream>>>(ws, yout);
  k_scan<5><<<1, 64, 0, stream>>>(ws, yout);
  k_scan<6><<<1, 64, 0, stream>>>(ws, yout);
  k_scan<12><<<1, 64, 0, stream>>>(ws, yout);
  k_out<<<79, 256, 0, stream>>>(ws, d_out);
}

// Round 8
// 1959.855 us; speedup vs baseline: 2.0832x; 1.0179x over previous
//
#include <hip/hip_runtime.h>
#include <hip/hip_bf16.h>
#include <stdint.h>
#include <type_traits>

#define SUBU 20
#define E_NO 2000
#define I_NO 500
#define T_DATA 20000
#define T_SYNK 200
#define HBAS 3
#define SBAS 3
#define TPAD 20096          // 1256 * 16

// workspace float offsets
#define OFF_SYN  0          // [20][TPAD]  c[s][t] = TK*(syn + theta + rowsum)
#define OFF_INE  401920     // [20][TPAD]
#define OFF_INI  803840     // [20][TPAD]  (reused as Y f32 by scan)
#define OFF_KE   1205760    // [20][200]
#define OFF_KI   1209760    // [20][200]
#define OFF_IIR  1213760    // [20][16] folded IIR consts (A-side TK-scaled)
#define OFF_MW   1214760    // [20][KSTORE]  mwp = -2*TK*m
#define OFF_MIDX 1215000    // [20][KSTORE] ints
#define OFF_PAR  1215240    // TK*(theta+rowsum)[20], wsub0, vo, ksel(int at +23)
#define OFF_FLAG 1215264    // int bf16 flag
#define OFF_Y    OFF_INI
#define KSTORE   12

#define TKC 2.8853900817779268f   // 2*log2(e)

__device__ __forceinline__ float bf2f(unsigned short u){
  unsigned v = ((unsigned)u) << 16; float f; __builtin_memcpy(&f, &v, 4); return f;
}
__device__ __forceinline__ float ldany(const void* p, int i, int bf){
  return bf ? bf2f(((const unsigned short*)p)[i]) : ((const float*)p)[i];
}
__device__ __forceinline__ float ex2(float x){ return __builtin_amdgcn_exp2f(x); }
__device__ __forceinline__ float rcpa(float x){ return __builtin_amdgcn_rcpf(x); }

// ------- prep (with fused dtype detection): kernels, IIR, tables, params --
__global__ __launch_bounds__(512) void k_prep(
    const void* Se, const void* Cden, const void* Wsyn, const void* Tausyn,
    const void* Dsyn, const void* Whist, const void* Tauhist, const void* Dhist,
    const void* Wsub, const void* Vo, const void* Theta, float* ws){
  int* wsi = (int*)ws;
  const int tx = threadIdx.x;
  __shared__ int found, mx;
  if (tx == 0){ found = 0; mx = 0; }
  __syncthreads();
  // dtype detect: S_e is exactly {0,1}; bf16 1.0 patterns in raw words
  {
    const unsigned* w = (const unsigned*)Se;
    int hit = 0;
    for (int i = tx; i < 8192; i += 512){
      unsigned x = w[i];
      if (x == 0x00003F80u || x == 0x3F803F80u) hit = 1;
    }
    if (hit) atomicOr(&found, 1);
  }
  __syncthreads();
  const int bf = found;
  if (tx == 0) wsi[OFF_FLAG] = bf;
  // synaptic kernels ke/ki [20][200]
  for (int idx = tx; idx < SUBU * T_SYNK; idx += 512){
    int s = idx / T_SYNK, t = idx % T_SYNK;
    for (int c = 0; c < 2; ++c){
      float delta = __expf(ldany(Dsyn, s*2 + c, bf));
      float acc = 0.f;
      for (int b = 0; b < SBAS; ++b){
        float tau = __expf(ldany(Tausyn, b*2 + c, bf));
        float w   = ldany(Wsyn, (s*SBAS + b)*2 + c, bf);
        float tt  = fmaxf((float)t - delta, 0.f) / tau;
        acc += w * tt * __expf(-tt);
      }
      ws[(c == 0 ? OFF_KE : OFF_KI) + s*T_SYNK + t] = acc;
    }
  }
  // folded per-lane IIR constants; A-side carries TK*w
  if (tx < SUBU * HBAS){
    int s = tx / HBAS, b = tx % HBAS;
    float tau = __expf(ldany(Tauhist, b, bf));
    float w   = TKC * ldany(Whist, s*HBAS + b, bf);
    float dl  = ldany(Dhist, s, bf);
    float rho = __expf(-1.f / tau);
    float e1  = __expf(-(1.f - dl) / tau);
    float g1  = ((1.f - dl) / tau) * e1;
    float kap = rho / tau;
    float* c = ws + OFF_IIR + s*16 + b*4;
    c[0] = rho;          // decay
    c[1] = w * kap;      // E -> A  (TK-scaled)
    c[2] = w * g1;       // y_new coeff into A (TK-scaled)
    c[3] = e1;           // y_new coeff into E (unscaled)
    if (b == 2){
      float e49 = __expf(-(49.f - dl) / tau);
      float g49 = ((49.f - dl) / tau) * e49;
      ws[OFF_IIR + s*16 + 12] = w * (rho*g49 + kap*e49);  // cA (TK-scaled)
      ws[OFF_IIR + s*16 + 13] = rho * e49;                // cE (unscaled)
    }
  }
  // sparse gather weights mwp = -2*TK*C_den*W_sub ; rowsum fold into PAR
  if (tx < SUBU){
    int s = tx, cnt = 0;
    float rowsum = 0.f;
    for (int sp = 0; sp < SUBU; ++sp){
      float c = ldany(Cden, s*SUBU + sp, bf);
      if (c != 0.f && cnt < KSTORE){
        float m = c * ldany(Wsub, sp, bf);
        rowsum += m;
        ws[OFF_MW + s*KSTORE + cnt]  = -2.f * TKC * m;
        wsi[OFF_MIDX + s*KSTORE + cnt] = sp;
        ++cnt;
      }
    }
    for (int k = cnt; k < KSTORE; ++k){
      ws[OFF_MW + s*KSTORE + k] = 0.f; wsi[OFF_MIDX + s*KSTORE + k] = 0;
    }
    atomicMax(&mx, cnt);
    ws[OFF_PAR + s] = TKC * (ldany(Theta, s, bf) + rowsum);
  }
  __syncthreads();
  if (tx == 0){
    ws[OFF_PAR + SUBU]     = ldany(Wsub, 0, bf);
    ws[OFF_PAR + SUBU + 1] = ldany(Vo, 0, bf);
    wsi[OFF_PAR + 23] = (mx <= 3) ? 3 : (mx <= 4 ? 4 : (mx <= 5 ? 5 :
                        (mx <= 6 ? 6 : 12)));
  }
}

// ------- skinny GEMM (4 waves/block): in_T[s][t] = sum_e S[t][e]*C[s][e] --
template<int BF>
__device__ __forceinline__ void gemm_impl(const void* S, const void* C, int W,
                                          float* dst, int t0, int lane){
  float acc[4][SUBU];
  #pragma unroll
  for (int r = 0; r < 4; ++r)
    #pragma unroll
    for (int s = 0; s < SUBU; ++s) acc[r][s] = 0.f;
  for (int e = lane; e < W; e += 64){
    float s0 = ldany(S, (t0+0)*W + e, BF);
    float s1 = ldany(S, (t0+1)*W + e, BF);
    float s2 = ldany(S, (t0+2)*W + e, BF);
    float s3 = ldany(S, (t0+3)*W + e, BF);
    #pragma unroll
    for (int s = 0; s < SUBU; ++s){
      float c = ldany(C, s*W + e, BF);
      acc[0][s] = fmaf(s0, c, acc[0][s]);
      acc[1][s] = fmaf(s1, c, acc[1][s]);
      acc[2][s] = fmaf(s2, c, acc[2][s]);
      acc[3][s] = fmaf(s3, c, acc[3][s]);
    }
  }
  #pragma unroll
  for (int r = 0; r < 4; ++r){
    #pragma unroll
    for (int s = 0; s < SUBU; ++s){
      float v = acc[r][s];
      #pragma unroll
      for (int m = 32; m >= 1; m >>= 1) v += __shfl_xor(v, m, 64);
      if (lane == 0) dst[s*TPAD + t0 + r] = v;
    }
  }
}

__global__ __launch_bounds__(256) void k_gemm(const void* S, const void* C, int W,
                                              float* dst, const int* flagp){
  const int wave = threadIdx.x >> 6, lane = threadIdx.x & 63;
  const int t0 = blockIdx.x * 16 + wave * 4;
  if (*flagp) gemm_impl<1>(S, C, W, dst, t0, lane);
  else        gemm_impl<0>(S, C, W, dst, t0, lane);
}

// ------- causal conv (+theta/rowsum fold, TK scale): c[s][t] --------------
__global__ __launch_bounds__(256) void k_conv(float* ws){
  const int s  = blockIdx.y;
  const int t0 = blockIdx.x * 256;
  const float* ine = ws + OFF_INE + s*TPAD;
  const float* ini = ws + OFF_INI + s*TPAD;
  __shared__ float eL[455], iL[455], keL[T_SYNK], kiL[T_SYNK];
  for (int j = threadIdx.x; j < 455; j += 256){
    int t = t0 - 199 + j;
    bool ok = (t >= 0 && t < TPAD);
    eL[j] = ok ? ine[t] : 0.f;
    iL[j] = ok ? ini[t] : 0.f;
  }
  for (int j = threadIdx.x; j < T_SYNK; j += 256){
    keL[j] = ws[OFF_KE + s*T_SYNK + j];
    kiL[j] = ws[OFF_KI + s*T_SYNK + j];
  }
  __syncthreads();
  int t = t0 + threadIdx.x;
  if (t < TPAD){
    float a0 = 0.f, a1 = 0.f;
    #pragma unroll 4
    for (int k = 0; k < T_SYNK; ++k){
      a0 = fmaf(keL[k], eL[threadIdx.x + 199 - k], a0);
      a1 = fmaf(kiL[k], iL[threadIdx.x + 199 - k], a1);
    }
    ws[OFF_SYN + s*TPAD + t] = fmaf(TKC, a0 + a1, ws[OFF_PAR + s]);
  }
}

// ------- static float4 component helpers ----------------------------------
__device__ __forceinline__ float get4(const float4& a, const float4& b,
                                      const float4& c, const float4& d, int u){
  const float4& q = (u < 4) ? a : ((u < 8) ? b : ((u < 12) ? c : d));
  int r = u & 3;
  return (r == 0) ? q.x : ((r == 1) ? q.y : ((r == 2) ? q.z : q.w));
}
__device__ __forceinline__ void set4(float4& a, float4& b, float4& c, float4& d,
                                     int u, float v){
  float4& q = (u < 4) ? a : ((u < 8) ? b : ((u < 12) ? c : d));
  int r = u & 3;
  if (r == 0) q.x = v; else if (r == 1) q.y = v; else if (r == 2) q.z = v; else q.w = v;
}

// ------- sequential scan: per-step DS = KM bpermutes ONLY -----------------
// y[t-50] taps batched: 8x ds_read_b64 at block start, 4x ds_write_b128 at
// block end. Ring row stride 68 floats (16B aligned; b128 tiles all banks).
template<int KM>
__global__ __launch_bounds__(64, 1) void k_scan(float* ws, float* yout){
  const int* wsi = (const int*)ws;
  if (wsi[OFF_PAR + 23] != KM) return;
  __shared__ float ring[64*68];
  const int lane = threadIdx.x;
  const int s = lane < SUBU ? lane : SUBU - 1;
  float* rbase = &ring[lane*68];
  {
    float4 z = make_float4(0.f, 0.f, 0.f, 0.f);
    float4* rq = (float4*)rbase;
    #pragma unroll
    for (int j = 0; j < 16; ++j) rq[j] = z;     // zero 64 ring entries
  }
  float mwp[KM]; int mad[KM];
  #pragma unroll
  for (int k = 0; k < KM; ++k){
    mwp[k] = ws[OFF_MW + s*KSTORE + k];
    mad[k] = wsi[OFF_MIDX + s*KSTORE + k] * 4;
  }
  const float* cc = ws + OFF_IIR + s*16;
  const float rh0 = cc[0],  kp0 = cc[1],  ay0 = cc[2],  ey0 = cc[3];
  const float rh1 = cc[4],  kp1 = cc[5],  ay1 = cc[6],  ey1 = cc[7];
  const float rh2 = cc[8],  kp2 = cc[9],  ay2 = cc[10], ey2 = cc[11];
  const float cA  = cc[12], cE  = cc[13];
  const float wsub0 = ws[OFF_PAR + SUBU];
  const float vo    = ws[OFF_PAR + SUBU + 1];
  const float* syncol = ws + OFF_SYN + s*TPAD;

  float A0=0.f,E0=0.f,A1=0.f,E1=0.f,A2=0.f,E2=0.f;
  float pb[KM];
  #pragma unroll
  for (int k = 0; k < KM; ++k) pb[k] = 0.5f;    // r for y=0
  float yprev = 0.f;                            // y[t-1]
  float4 u0 = *(const float4*)(syncol + 0);
  float4 u1 = *(const float4*)(syncol + 4);
  float4 u2 = *(const float4*)(syncol + 8);
  float4 u3 = *(const float4*)(syncol + 12);
  float4 n0, n1, n2, n3;
  float xpre = u0.x;                            // X[0] partial (h = 0)

  auto block16 = [&](auto PH_, int tbase, float4& b0, float4& b1, float4& b2,
                     float4& b3, float4& p0, float4& p1, float4& p2, float4& p3){
    constexpr int PH = decltype(PH_)::value;    // ring phase = tbase & 63
    const float4* src = (const float4*)(syncol + tbase + 16);
    p0 = src[0]; p1 = src[1]; p2 = src[2]; p3 = src[3];
    // batched correction-tap reads: yold[i] = y[tbase-50+i], ring pos (PH+14+i)&63
    float yold[16];
    if constexpr (PH != 48){
      #pragma unroll
      for (int j = 0; j < 8; ++j){
        float2 v = *(const float2*)(rbase + PH + 14 + 2*j);
        yold[2*j] = v.x; yold[2*j+1] = v.y;
      }
    } else {
      float2 v = *(const float2*)(rbase + 62);
      yold[0] = v.x; yold[1] = v.y;
      #pragma unroll
      for (int j = 0; j < 7; ++j){
        float2 v2 = *(const float2*)(rbase + 2*j);
        yold[2 + 2*j] = v2.x; yold[3 + 2*j] = v2.y;
      }
    }
    float4 ob0, ob1, ob2, ob3;                  // outputs
    float4 yb0, yb1, yb2, yb3;                  // y's for ring write
    #pragma unroll
    for (int u = 0; u < 16; ++u){
      // X[t] = xpre + sum_k mwp[k]*r_gathered[k]   (mwp = -2*TK*m)
      float acc0 = fmaf(mwp[0], pb[0], xpre);
      float acc1 = (KM > 1) ? mwp[1] * pb[1] : 0.f;
      #pragma unroll
      for (int k = 2; k < KM; ++k){
        if (k & 1) acc1 = fmaf(mwp[k], pb[k], acc1);
        else       acc0 = fmaf(mwp[k], pb[k], acc0);
      }
      float X  = acc0 + acc1;
      float r  = rcpa(ex2(X) + 1.f);
      // critical: issue next-step gathers immediately (only DS ops in queue)
      int rb = __float_as_int(r);
      #pragma unroll
      for (int k = 0; k < KM; ++k)
        pb[k] = __int_as_float(__builtin_amdgcn_ds_bpermute(mad[k], rb));
      float y = fmaf(-2.f, r, 1.f);             // y[t]
      float ro = yold[u];                       // y[t-50] (batch-prefetched)
      // folded IIR -> h[t+1]; input tap is y[t-1]
      float A0n = fmaf(rh0, A0, fmaf(kp0, E0, ay0 * yprev));
      E0 = fmaf(rh0, E0, ey0 * yprev); A0 = A0n;
      float A1n = fmaf(rh1, A1, fmaf(kp1, E1, ay1 * yprev));
      E1 = fmaf(rh1, E1, ey1 * yprev); A1 = A1n;
      float A2n = fmaf(rh2, A2, fmaf(kp2, E2, fmaf(-cA, ro, ay2 * yprev)));
      E2 = fmaf(rh2, E2, fmaf(-cE, ro, ey2 * yprev)); A2 = A2n;
      float h = (A0 + A1) + A2;
      float cn = (u < 15) ? get4(b0, b1, b2, b3, u + 1) : p0.x;
      xpre = cn + h;
      yprev = y;
      set4(yb0, yb1, yb2, yb3, u, y);
      set4(ob0, ob1, ob2, ob3, u, fmaf(y, wsub0, vo));
    }
    // batched ring writes: y[tbase..tbase+15] at ring pos PH..PH+15
    {
      float4* wq = (float4*)(rbase + PH);
      wq[0] = yb0; wq[1] = yb1; wq[2] = yb2; wq[3] = yb3;
    }
    if (lane == 0 && tbase + 16 <= T_DATA){
      float4* q = (float4*)(yout + tbase);
      q[0] = ob0; q[1] = ob1; q[2] = ob2; q[3] = ob3;
    }
  };

  using P0  = std::integral_constant<int,0>;
  using P16 = std::integral_constant<int,16>;
  using P32 = std::integral_constant<int,32>;
  using P48 = std::integral_constant<int,48>;
  #pragma unroll 1
  for (int ib2 = 0; ib2 < 314; ++ib2){          // 314*64 = 20096 steps
    const int tb = ib2 * 64;
    block16(P0{},  tb,      u0, u1, u2, u3, n0, n1, n2, n3);
    block16(P16{}, tb + 16, n0, n1, n2, n3, u0, u1, u2, u3);
    block16(P32{}, tb + 32, u0, u1, u2, u3, n0, n1, n2, n3);
    block16(P48{}, tb + 48, n0, n1, n2, n3, u0, u1, u2, u3);
  }
}

// ------- epilogue: f32 Y -> output dtype ----------------------------------
__global__ __launch_bounds__(256) void k_out(const float* ws, void* outp){
  const int* wsi = (const int*)ws;
  const int bf = wsi[OFF_FLAG];
  int i = blockIdx.x * 256 + threadIdx.x;
  if (i < T_DATA){
    float v = ws[OFF_Y + i];
    if (bf) ((__hip_bfloat16*)outp)[i] = __float2bfloat16(v);
    else    ((float*)outp)[i] = v;
  }
}

// --------------------------------------------------------------------------
extern "C" void kernel_launch(void* const* d_in, const int* in_sizes, int n_in,
                              void* d_out, int out_size, void* d_ws, size_t ws_size,
                              hipStream_t stream){
  const void* S_e   = d_in[0];
  const void* S_i   = d_in[1];
  const void* C_den = d_in[2];
  const void* C_e   = d_in[3];
  const void* C_i   = d_in[4];
  const void* W_syn = d_in[5];
  const void* Tau_s = d_in[6];
  const void* D_syn = d_in[7];
  const void* W_hst = d_in[8];
  const void* Tau_h = d_in[9];
  const void* D_hst = d_in[10];
  const void* W_sub = d_in[11];
  const void* V_o   = d_in[12];
  const void* Theta = d_in[13];
  float* ws = (float*)d_ws;
  int* flagp = (int*)(ws + OFF_FLAG);

  k_prep<<<1, 512, 0, stream>>>(S_e, C_den, W_syn, Tau_s, D_syn, W_hst, Tau_h,
                                D_hst, W_sub, V_o, Theta, ws);
  k_gemm<<<1250, 256, 0, stream>>>(S_e, C_e, E_NO, ws + OFF_INE, flagp);
  k_gemm<<<1250, 256, 0, stream>>>(S_i, C_i, I_NO, ws + OFF_INI, flagp);
  dim3 cgrid(79, 20);
  k_conv<<<cgrid, 256, 0, stream>>>(ws);
  float* yout = ws + OFF_Y;
  k_scan<3><<<1, 64, 0, stream>>>(ws, yout);
  k_scan<4><<<1, 64, 0, stream>>>(ws, yout);
  k_scan<5><<<1, 64, 0, stream>>>(ws, yout);
  k_scan<6><<<1, 64, 0, stream>>>(ws, yout);
  k_scan<12><<<1, 64, 0, stream>>>(ws, yout);
  k_out<<<79, 256, 0, stream>>>(ws, d_out);
}